// Round 9
// baseline (186.164 us; speedup 1.0000x reference)
//
#include <hip/hip_runtime.h>
#include <hip/hip_fp16.h>
#include <math.h>

// ---------------------------------------------------------------------------
// GCN. R22 = R21 (verified 183.8 us) with k_p2f DELETED:
//  - Gathers are now half-bucket blocks (64 nodes, 512 threads) that build
//    their own edge lists in LDS: hist (filtered to their 64 locals) ->
//    64-wide scan -> rank pass into colw_s[1024] (4 KB) -> per-node
//    register-accumulation edge loop reading indices from LDS. dinv is
//    recomputed locally from the hist (global dinv array deleted).
//  - k_mm computes dinv the same way: filtered hist of its bucket's ebuf
//    region (~5 iters/thread), overlapped with the GEMM.
//  - colw / row_ptr / row_end / dinv global arrays deleted (~15 MB traffic).
// 5 dispatches: memset(gcnt), k_scatter, k_mm, k_gather_mm, k_gather_head.
// k_scatter (fixed-capacity bucket regions + block-level atomic
// reservations) unchanged from R21. t' rows pre-scaled by dinv[row]:
//   agg[d] = relu(b + dinv[d] * (sum_e t'[src_e] + t'[d]))
// 512-thread gathers (not 1024): at ~84 VGPR this keeps >=24 waves/CU;
// 1024-thread blocks would cliff to 16 waves if VGPR > 64 (R18 lesson).
// ---------------------------------------------------------------------------

#define TPB1   1024         // scatter block size
#define EBLKS  256          // scatter grid
#define BSH    7            // 128 nodes per bucket
#define BNODES (1 << BSH)
#define CAPSH  11           // 2048 slots per bucket region
#define CAP    (1 << CAPSH)
#define HCAP   1024         // colw_s capacity per half-bucket (mean 640, +15 sigma)

// k_scatter: per block: LDS hist of its edge chunk -> global reservation
// (one atomic-return per non-empty bucket) -> LDS cursors -> scatter.
__global__ __launch_bounds__(TPB1)
void k_scatter(const int* __restrict__ src, const int* __restrict__ dst,
               int* __restrict__ gcnt, int* __restrict__ ebuf,
               int E, int CH, int NBC) {
    __shared__ int h[1024];     // hist, then absolute cursors
    int tid = threadIdx.x, b = blockIdx.x;
    h[tid] = 0;
    __syncthreads();
    int beg = b * CH, end = min(E, beg + CH);
    if (beg < end) {
        int nfull = (end - beg) & ~3;
        for (int i = beg + tid * 4; i < beg + nfull; i += TPB1 * 4) {
            int4 d = *(const int4*)&dst[i];
            atomicAdd(&h[d.x >> BSH], 1);
            atomicAdd(&h[d.y >> BSH], 1);
            atomicAdd(&h[d.z >> BSH], 1);
            atomicAdd(&h[d.w >> BSH], 1);
        }
        if (tid < (end - beg) - nfull)
            atomicAdd(&h[dst[beg + nfull + tid] >> BSH], 1);
    }
    __syncthreads();
    // reserve: h[c] <- absolute ebuf cursor for this block's share of bucket c
    for (int c = tid; c < NBC; c += TPB1) {
        int n = h[c];
        int base = (n > 0) ? atomicAdd(&gcnt[c], n) : 0;
        h[c] = (c << CAPSH) + base;
    }
    __syncthreads();
    if (beg >= end) return;
    int nfull = (end - beg) & ~3;
    for (int i = beg + tid * 4; i < beg + nfull; i += TPB1 * 4) {
        int4 s4 = *(const int4*)&src[i];
        int4 d4 = *(const int4*)&dst[i];
        int p0 = atomicAdd(&h[d4.x >> BSH], 1);
        int p1 = atomicAdd(&h[d4.y >> BSH], 1);
        int p2 = atomicAdd(&h[d4.z >> BSH], 1);
        int p3 = atomicAdd(&h[d4.w >> BSH], 1);
        ebuf[p0] = (s4.x << BSH) | (d4.x & (BNODES - 1));
        ebuf[p1] = (s4.y << BSH) | (d4.y & (BNODES - 1));
        ebuf[p2] = (s4.z << BSH) | (d4.z & (BNODES - 1));
        ebuf[p3] = (s4.w << BSH) | (d4.w & (BNODES - 1));
    }
    if (tid < (end - beg) - nfull) {
        int i = beg + nfull + tid;
        int d = dst[i];
        int p = atomicAdd(&h[d >> BSH], 1);
        ebuf[p] = (src[i] << BSH) | (d & (BNODES - 1));
    }
}

// Dense GEMM: [n,64] @ [64,64], fp32 in, out = fp16 t' = dinv[row]*(row@W).
// dinv computed in-kernel: filtered hist of bucket's ebuf region (overlaps
// GEMM compute). Block b: bucket c=b>>1, locals [lb, lb+64), rows 64b..
__launch_bounds__(256)
__global__ void k_mm(const float* __restrict__ in, const float* __restrict__ W,
                     const int* __restrict__ ebuf, const int* __restrict__ gcnt,
                     __half* __restrict__ out, int n) {
    __shared__ float in_s[64 * 68];
    __shared__ float w_s[64 * 64];
    __shared__ int   cnt[64];

    const int tid  = threadIdx.x;
    const int row0 = blockIdx.x * 64;
    const int c    = blockIdx.x >> 1;
    const int lb   = (blockIdx.x & 1) << 6;

    for (int i4 = tid; i4 < (64 * 64) / 4; i4 += 256)
        ((float4*)w_s)[i4] = ((const float4*)W)[i4];

    for (int idx = tid; idx < 64 * 16; idx += 256) {
        int r  = idx >> 4;
        int c4 = idx & 15;
        float4 v;
        if (row0 + r < n)
            v = *(const float4*)(in + (size_t)(row0 + r) * 64 + c4 * 4);
        else
            v = make_float4(0.f, 0.f, 0.f, 0.f);
        *(float4*)&in_s[r * 68 + c4 * 4] = v;
    }
    if (tid < 64) cnt[tid] = 0;
    __syncthreads();        // staging + cnt init done

    // degree hist for this block's 64 rows (loads overlap GEMM via waves)
    {
        const int ebeg = c << CAPSH;
        const int eend = ebeg + gcnt[c];
        for (int i = ebeg + tid; i < eend; i += 256) {
            int lr = (ebuf[i] & (BNODES - 1)) - lb;
            if ((unsigned)lr < 64u) atomicAdd(&cnt[lr], 1);
        }
    }

    constexpr int CPT = 4;
    const int tx = tid & 15;
    const int ty = tid >> 4;

    float acc[4][CPT];
#pragma unroll
    for (int r = 0; r < 4; ++r)
#pragma unroll
        for (int cc = 0; cc < CPT; ++cc) acc[r][cc] = 0.f;

#pragma unroll 4
    for (int k = 0; k < 64; ++k) {
        float b[CPT];
#pragma unroll
        for (int cc = 0; cc < CPT; ++cc) b[cc] = w_s[k * 64 + tx * CPT + cc];
#pragma unroll
        for (int r = 0; r < 4; ++r) {
            float a = in_s[(ty * 4 + r) * 68 + k];
#pragma unroll
            for (int cc = 0; cc < CPT; ++cc)
                acc[r][cc] = fmaf(a, b[cc], acc[r][cc]);
        }
    }
    __syncthreads();        // all hist atomics complete (hist precedes FMA)

#pragma unroll
    for (int r = 0; r < 4; ++r) {
        int lrow = ty * 4 + r;
        int row  = row0 + lrow;
        if (row >= n) continue;
        float dd = rsqrtf((float)(cnt[lrow] + 1));
        __half2 p0 = __floats2half2_rn(acc[r][0] * dd, acc[r][1] * dd);
        __half2 p1 = __floats2half2_rn(acc[r][2] * dd, acc[r][3] * dd);
        uint2 u = make_uint2(*(unsigned*)&p0, *(unsigned*)&p1);
        *(uint2*)(out + (size_t)row * 64 + tx * 4) = u;
    }
    // zero sentinel row n (tail edges in gather read it)
    if (blockIdx.x == 0 && tid < 16)
        *(uint2*)(out + (size_t)n * 64 + tid * 4) = make_uint2(0u, 0u);
}

// Gather (layer 1) + fused mm2, half-bucket block (64 nodes, 512 threads).
// Builds its edge lists in LDS (hist->scan->rank), computes dinv locally.
// aggrow = relu(b1 + dinv[d]*(sum t'[src] + t'[d]))  (fp16 in LDS)
// t2'[d] = dinv[d] * (aggrow @ W2)   (fp16 out, + zero sentinel row N)
__global__ __launch_bounds__(512)
void k_gather_mm(const int* __restrict__ ebuf, const int* __restrict__ gcnt,
                 const float* __restrict__ bias, const __half* __restrict__ t,
                 const float* __restrict__ W2, __half* __restrict__ t2, int N) {
    __shared__ float  w_s[64 * 64];     // 16 KB
    __shared__ __half aggs[64][72];     // 9 KB
    __shared__ int    colw_s[HCAP];     // 4 KB
    __shared__ int    cnt[64];
    __shared__ int    ofs[64];
    __shared__ int    scn[64];
    __shared__ float  dinv_s[64];

    const int tid = threadIdx.x;
    const int c   = blockIdx.x >> 1;
    const int lb  = (blockIdx.x & 1) << 6;

    for (int i4 = tid; i4 < (64 * 64) / 4; i4 += 512)
        ((float4*)w_s)[i4] = ((const float4*)W2)[i4];

    if (tid < 64) cnt[tid] = 0;
    __syncthreads();
    const int ebeg = c << CAPSH;
    const int eend = ebeg + gcnt[c];
    for (int i = ebeg + tid; i < eend; i += 512) {
        int lr = (ebuf[i] & (BNODES - 1)) - lb;
        if ((unsigned)lr < 64u) atomicAdd(&cnt[lr], 1);
    }
    __syncthreads();
    int a = (tid < 64) ? cnt[tid] : 0;
    if (tid < 64) scn[tid] = a;
    __syncthreads();
    for (int off = 1; off < 64; off <<= 1) {
        int x = (tid < 64 && tid >= off) ? scn[tid - off] : 0;
        __syncthreads();
        if (tid < 64) scn[tid] += x;
        __syncthreads();
    }
    if (tid < 64) {
        ofs[tid]    = scn[tid] - a;     // exclusive, local to colw_s
        dinv_s[tid] = rsqrtf((float)(a + 1));
        cnt[tid]    = 0;                // reuse as rank cursor
    }
    __syncthreads();
    for (int i = ebeg + tid; i < eend; i += 512) {
        int e  = ebuf[i];
        int lr = (e & (BNODES - 1)) - lb;
        if ((unsigned)lr < 64u) {
            int r = atomicAdd(&cnt[lr], 1);
            colw_s[ofs[lr] + r] = e >> BSH;
        }
    }
    __syncthreads();                    // cnt[l] == degree again

    const int p = tid & 7;
    const int l = tid >> 3;             // 0..63
    const int d = (c << BSH) + lb + l;
    const int eb = ofs[l];
    const int ee = eb + cnt[l];

    float acc[8];
#pragma unroll
    for (int k = 0; k < 8; ++k) acc[k] = 0.f;

    for (int e = eb; e < ee; e += 4) {
        int v0 = colw_s[e];
        int v1 = (e + 1 < ee) ? colw_s[e + 1] : N;   // N = zero sentinel row
        int v2 = (e + 2 < ee) ? colw_s[e + 2] : N;
        int v3 = (e + 3 < ee) ? colw_s[e + 3] : N;
        uint4 a0 = *(const uint4*)(t + (size_t)v0 * 64 + p * 8);
        uint4 a1 = *(const uint4*)(t + (size_t)v1 * 64 + p * 8);
        uint4 a2 = *(const uint4*)(t + (size_t)v2 * 64 + p * 8);
        uint4 a3 = *(const uint4*)(t + (size_t)v3 * 64 + p * 8);
        float2 f;
        f = __half22float2(*(__half2*)&a0.x); acc[0] += f.x; acc[1] += f.y;
        f = __half22float2(*(__half2*)&a0.y); acc[2] += f.x; acc[3] += f.y;
        f = __half22float2(*(__half2*)&a0.z); acc[4] += f.x; acc[5] += f.y;
        f = __half22float2(*(__half2*)&a0.w); acc[6] += f.x; acc[7] += f.y;
        f = __half22float2(*(__half2*)&a1.x); acc[0] += f.x; acc[1] += f.y;
        f = __half22float2(*(__half2*)&a1.y); acc[2] += f.x; acc[3] += f.y;
        f = __half22float2(*(__half2*)&a1.z); acc[4] += f.x; acc[5] += f.y;
        f = __half22float2(*(__half2*)&a1.w); acc[6] += f.x; acc[7] += f.y;
        f = __half22float2(*(__half2*)&a2.x); acc[0] += f.x; acc[1] += f.y;
        f = __half22float2(*(__half2*)&a2.y); acc[2] += f.x; acc[3] += f.y;
        f = __half22float2(*(__half2*)&a2.z); acc[4] += f.x; acc[5] += f.y;
        f = __half22float2(*(__half2*)&a2.w); acc[6] += f.x; acc[7] += f.y;
        f = __half22float2(*(__half2*)&a3.x); acc[0] += f.x; acc[1] += f.y;
        f = __half22float2(*(__half2*)&a3.y); acc[2] += f.x; acc[3] += f.y;
        f = __half22float2(*(__half2*)&a3.z); acc[4] += f.x; acc[5] += f.y;
        f = __half22float2(*(__half2*)&a3.w); acc[6] += f.x; acc[7] += f.y;
    }

    if (d < N) {
        float dd = dinv_s[l];
        uint4 aa = *(const uint4*)(t + (size_t)d * 64 + p * 8);
        float4 b0 = *(const float4*)&bias[p * 8];
        float4 b1 = *(const float4*)&bias[p * 8 + 4];
        float2 s0 = __half22float2(*(__half2*)&aa.x);
        float2 s1 = __half22float2(*(__half2*)&aa.y);
        float2 s2 = __half22float2(*(__half2*)&aa.z);
        float2 s3 = __half22float2(*(__half2*)&aa.w);
        float o0 = fmaxf(fmaf(dd, acc[0] + s0.x, b0.x), 0.f);
        float o1 = fmaxf(fmaf(dd, acc[1] + s0.y, b0.y), 0.f);
        float o2 = fmaxf(fmaf(dd, acc[2] + s1.x, b0.z), 0.f);
        float o3 = fmaxf(fmaf(dd, acc[3] + s1.y, b0.w), 0.f);
        float o4 = fmaxf(fmaf(dd, acc[4] + s2.x, b1.x), 0.f);
        float o5 = fmaxf(fmaf(dd, acc[5] + s2.y, b1.y), 0.f);
        float o6 = fmaxf(fmaf(dd, acc[6] + s3.x, b1.z), 0.f);
        float o7 = fmaxf(fmaf(dd, acc[7] + s3.y, b1.w), 0.f);
        __half2 h0 = __floats2half2_rn(o0, o1);
        __half2 h1 = __floats2half2_rn(o2, o3);
        __half2 h2 = __floats2half2_rn(o4, o5);
        __half2 h3 = __floats2half2_rn(o6, o7);
        *(uint4*)&aggs[l][p * 8] = make_uint4(*(unsigned*)&h0, *(unsigned*)&h1,
                                              *(unsigned*)&h2, *(unsigned*)&h3);
    }
    __syncthreads();        // w_s staged + all 8 lanes of each group wrote aggs

    if (d < N) {
        float dd = dinv_s[l];
        float a0 = 0.f, a1 = 0.f, a2 = 0.f, a3 = 0.f;
        float a4 = 0.f, a5 = 0.f, a6 = 0.f, a7 = 0.f;
#pragma unroll
        for (int k0 = 0; k0 < 64; k0 += 8) {
            uint4 u = *(const uint4*)&aggs[l][k0];
            float2 f0 = __half22float2(*(__half2*)&u.x);
            float2 f1 = __half22float2(*(__half2*)&u.y);
            float2 f2 = __half22float2(*(__half2*)&u.z);
            float2 f3 = __half22float2(*(__half2*)&u.w);
            float av[8] = {f0.x, f0.y, f1.x, f1.y, f2.x, f2.y, f3.x, f3.y};
#pragma unroll
            for (int j = 0; j < 8; ++j) {
                const float* wr = &w_s[(k0 + j) * 64 + p * 8];   // broadcast/grp
                float4 w0 = *(const float4*)&wr[0];
                float4 w1 = *(const float4*)&wr[4];
                a0 = fmaf(av[j], w0.x, a0);
                a1 = fmaf(av[j], w0.y, a1);
                a2 = fmaf(av[j], w0.z, a2);
                a3 = fmaf(av[j], w0.w, a3);
                a4 = fmaf(av[j], w1.x, a4);
                a5 = fmaf(av[j], w1.y, a5);
                a6 = fmaf(av[j], w1.z, a6);
                a7 = fmaf(av[j], w1.w, a7);
            }
        }
        __half2 q0 = __floats2half2_rn(a0 * dd, a1 * dd);
        __half2 q1 = __floats2half2_rn(a2 * dd, a3 * dd);
        __half2 q2 = __floats2half2_rn(a4 * dd, a5 * dd);
        __half2 q3 = __floats2half2_rn(a6 * dd, a7 * dd);
        uint4 u = make_uint4(*(unsigned*)&q0, *(unsigned*)&q1,
                             *(unsigned*)&q2, *(unsigned*)&q3);
        *(uint4*)(t2 + (size_t)d * 64 + p * 8) = u;
    }
    // zero sentinel row N of t2 (tail edges in gather2 read it)
    if (blockIdx.x == 0 && tid < 16)
        *(uint2*)(t2 + (size_t)N * 64 + tid * 4) = make_uint2(0u, 0u);
}

// Gather (layer 2) + fused classifier head, half-bucket block (64 nodes):
// agg_row = relu(b2 + dinv[d]*(sum t'[src] + t'[d]))  (kept in LDS, fp32)
// out[d]  = agg_row @ Wl + bl   (each 8-lane group: lane p -> cols 4p..4p+3)
__global__ __launch_bounds__(512)
void k_gather_head(const int* __restrict__ ebuf, const int* __restrict__ gcnt,
                   const float* __restrict__ bias, const __half* __restrict__ t,
                   const float* __restrict__ Wl, const float* __restrict__ bl,
                   float* __restrict__ out, int N) {
    __shared__ float wl_s[64 * 32];     // 8 KB
    __shared__ float aggs[64][68];      // 17 KB, stride 68
    __shared__ int   colw_s[HCAP];      // 4 KB
    __shared__ int   cnt[64];
    __shared__ int   ofs[64];
    __shared__ int   scn[64];
    __shared__ float dinv_s[64];

    const int tid = threadIdx.x;
    const int c   = blockIdx.x >> 1;
    const int lb  = (blockIdx.x & 1) << 6;

    for (int i4 = tid; i4 < (64 * 32) / 4; i4 += 512)
        ((float4*)wl_s)[i4] = ((const float4*)Wl)[i4];

    if (tid < 64) cnt[tid] = 0;
    __syncthreads();
    const int ebeg = c << CAPSH;
    const int eend = ebeg + gcnt[c];
    for (int i = ebeg + tid; i < eend; i += 512) {
        int lr = (ebuf[i] & (BNODES - 1)) - lb;
        if ((unsigned)lr < 64u) atomicAdd(&cnt[lr], 1);
    }
    __syncthreads();
    int a = (tid < 64) ? cnt[tid] : 0;
    if (tid < 64) scn[tid] = a;
    __syncthreads();
    for (int off = 1; off < 64; off <<= 1) {
        int x = (tid < 64 && tid >= off) ? scn[tid - off] : 0;
        __syncthreads();
        if (tid < 64) scn[tid] += x;
        __syncthreads();
    }
    if (tid < 64) {
        ofs[tid]    = scn[tid] - a;
        dinv_s[tid] = rsqrtf((float)(a + 1));
        cnt[tid]    = 0;
    }
    __syncthreads();
    for (int i = ebeg + tid; i < eend; i += 512) {
        int e  = ebuf[i];
        int lr = (e & (BNODES - 1)) - lb;
        if ((unsigned)lr < 64u) {
            int r = atomicAdd(&cnt[lr], 1);
            colw_s[ofs[lr] + r] = e >> BSH;
        }
    }
    __syncthreads();

    const int p = tid & 7;
    const int l = tid >> 3;
    const int d = (c << BSH) + lb + l;
    const int eb = ofs[l];
    const int ee = eb + cnt[l];

    float acc[8];
#pragma unroll
    for (int k = 0; k < 8; ++k) acc[k] = 0.f;

    for (int e = eb; e < ee; e += 4) {
        int v0 = colw_s[e];
        int v1 = (e + 1 < ee) ? colw_s[e + 1] : N;
        int v2 = (e + 2 < ee) ? colw_s[e + 2] : N;
        int v3 = (e + 3 < ee) ? colw_s[e + 3] : N;
        uint4 a0 = *(const uint4*)(t + (size_t)v0 * 64 + p * 8);
        uint4 a1 = *(const uint4*)(t + (size_t)v1 * 64 + p * 8);
        uint4 a2 = *(const uint4*)(t + (size_t)v2 * 64 + p * 8);
        uint4 a3 = *(const uint4*)(t + (size_t)v3 * 64 + p * 8);
        float2 f;
        f = __half22float2(*(__half2*)&a0.x); acc[0] += f.x; acc[1] += f.y;
        f = __half22float2(*(__half2*)&a0.y); acc[2] += f.x; acc[3] += f.y;
        f = __half22float2(*(__half2*)&a0.z); acc[4] += f.x; acc[5] += f.y;
        f = __half22float2(*(__half2*)&a0.w); acc[6] += f.x; acc[7] += f.y;
        f = __half22float2(*(__half2*)&a1.x); acc[0] += f.x; acc[1] += f.y;
        f = __half22float2(*(__half2*)&a1.y); acc[2] += f.x; acc[3] += f.y;
        f = __half22float2(*(__half2*)&a1.z); acc[4] += f.x; acc[5] += f.y;
        f = __half22float2(*(__half2*)&a1.w); acc[6] += f.x; acc[7] += f.y;
        f = __half22float2(*(__half2*)&a2.x); acc[0] += f.x; acc[1] += f.y;
        f = __half22float2(*(__half2*)&a2.y); acc[2] += f.x; acc[3] += f.y;
        f = __half22float2(*(__half2*)&a2.z); acc[4] += f.x; acc[5] += f.y;
        f = __half22float2(*(__half2*)&a2.w); acc[6] += f.x; acc[7] += f.y;
        f = __half22float2(*(__half2*)&a3.x); acc[0] += f.x; acc[1] += f.y;
        f = __half22float2(*(__half2*)&a3.y); acc[2] += f.x; acc[3] += f.y;
        f = __half22float2(*(__half2*)&a3.z); acc[4] += f.x; acc[5] += f.y;
        f = __half22float2(*(__half2*)&a3.w); acc[6] += f.x; acc[7] += f.y;
    }

    if (d < N) {
        float dd = dinv_s[l];
        uint4 aa = *(const uint4*)(t + (size_t)d * 64 + p * 8);
        float4 b0 = *(const float4*)&bias[p * 8];
        float4 b1 = *(const float4*)&bias[p * 8 + 4];
        float2 s0 = __half22float2(*(__half2*)&aa.x);
        float2 s1 = __half22float2(*(__half2*)&aa.y);
        float2 s2 = __half22float2(*(__half2*)&aa.z);
        float2 s3 = __half22float2(*(__half2*)&aa.w);
        float o0 = fmaxf(fmaf(dd, acc[0] + s0.x, b0.x), 0.f);
        float o1 = fmaxf(fmaf(dd, acc[1] + s0.y, b0.y), 0.f);
        float o2 = fmaxf(fmaf(dd, acc[2] + s1.x, b0.z), 0.f);
        float o3 = fmaxf(fmaf(dd, acc[3] + s1.y, b0.w), 0.f);
        float o4 = fmaxf(fmaf(dd, acc[4] + s2.x, b1.x), 0.f);
        float o5 = fmaxf(fmaf(dd, acc[5] + s2.y, b1.y), 0.f);
        float o6 = fmaxf(fmaf(dd, acc[6] + s3.x, b1.z), 0.f);
        float o7 = fmaxf(fmaf(dd, acc[7] + s3.y, b1.w), 0.f);
        *(float4*)&aggs[l][p * 8]     = make_float4(o0, o1, o2, o3);
        *(float4*)&aggs[l][p * 8 + 4] = make_float4(o4, o5, o6, o7);
    }
    __syncthreads();        // wl_s loaded + all 8 lanes of each group wrote aggs

    if (d < N) {
        float a0 = 0.f, a1 = 0.f, a2 = 0.f, a3 = 0.f;
#pragma unroll 8
        for (int k = 0; k < 64; ++k) {
            float av = aggs[l][k];                          // broadcast in group
            float4 w = ((const float4*)&wl_s[k * 32])[p];   // conflict-free
            a0 = fmaf(av, w.x, a0);
            a1 = fmaf(av, w.y, a1);
            a2 = fmaf(av, w.z, a2);
            a3 = fmaf(av, w.w, a3);
        }
        float4 bb = *(const float4*)&bl[p * 4];
        *(float4*)&out[(size_t)d * 32 + p * 4] =
            make_float4(a0 + bb.x, a1 + bb.y, a2 + bb.z, a3 + bb.w);
    }
}

extern "C" void kernel_launch(void* const* d_in, const int* in_sizes, int n_in,
                              void* d_out, int out_size, void* d_ws, size_t ws_size,
                              hipStream_t stream) {
    const float* x  = (const float*)d_in[0];
    const int*   ei = (const int*)d_in[1];
    const float* W1 = (const float*)d_in[2];
    const float* b1 = (const float*)d_in[3];
    const float* W2 = (const float*)d_in[4];
    const float* b2 = (const float*)d_in[5];
    const float* Wl = (const float*)d_in[6];
    const float* bl = (const float*)d_in[7];
    float*       out = (float*)d_out;

    const int N = in_sizes[0] / 64;
    const int E = in_sizes[1] / 2;
    const int* srcp = ei;
    const int* dstp = ei + E;

    const int NBC = (N + BNODES - 1) / BNODES;               // buckets (782)
    const int CH  = (((E + EBLKS - 1) / EBLKS) + 3) & ~3;    // chunk, mult of 4

    char*  ws  = (char*)d_ws;
    size_t off = 0;
    auto alloc = [&](size_t bytes) -> void* {
        void* p = (void*)(ws + off);
        off += (bytes + 255) & ~(size_t)255;
        return p;
    };
    int*    gcnt = (int*)alloc((size_t)NBC * 4);
    int*    ebuf = (int*)alloc((size_t)NBC * CAP * 4);       // 6.4 MB
    __half* t1   = (__half*)alloc((size_t)(N + 1) * 64 * 2); // +sentinel
    __half* t2   = (__half*)alloc((size_t)(N + 1) * 64 * 2); // separate:
    // k_gather_mm reads t1 rows (random, cross-block) while writing t2.

    const int nb_mm = (N + 63) / 64;    // also = half-bucket gather grid
    const int nb_g  = (N + 63) / 64;

    // --- CSR-lite build: memset + reservation-scatter ---
    hipMemsetAsync(gcnt, 0, (size_t)NBC * 4, stream);
    k_scatter<<<EBLKS, TPB1, 0, stream>>>(srcp, dstp, gcnt, ebuf, E, CH, NBC);

    // --- layer 1: t1' = dinv * (x @ W1)  (dinv from in-kernel hist) ---
    k_mm<<<nb_mm, 256, 0, stream>>>(x, W1, ebuf, gcnt, t1, N);

    // --- gather1 (LDS rank) + fused mm2: t2' = dinv * (relu-agg1 @ W2) ---
    k_gather_mm<<<nb_g, 512, 0, stream>>>(ebuf, gcnt, b1, t1, W2, t2, N);

    // --- gather2 (LDS rank) + fused head: out = relu-agg2 @ Wl + bl ---
    k_gather_head<<<nb_g, 512, 0, stream>>>(ebuf, gcnt, b2, t2, Wl, bl, out, N);
}

// Round 10
// 184.384 us; speedup vs baseline: 1.0097x; 1.0097x over previous
//
#include <hip/hip_runtime.h>
#include <hip/hip_fp16.h>
#include <math.h>

// ---------------------------------------------------------------------------
// GCN. R23 = R21 (verified 183.8 us; R22's in-gather rank pass REVERTED:
// duplicated rank work in both gathers, +2.4) + 4-ALIGNED SENTINEL-PADDED
// colw segments:
//  - k_p2f scans padded degrees ap=(a+3)&~3 -> every node's colw segment
//    starts 4-aligned (base is 2048-aligned); after the rank pass the <=3
//    pad slots per node are filled with sentinel index N (t row N = zeros).
//  - Gather edge loop: ONE aligned int4 colw load + 4 uint4 row loads per
//    iteration, NO per-element tail guards (pads are sentinels). Load
//    instructions in the hot loop drop 8 -> 5 per lane-iter (-37%); the
//    compare/select tail chain disappears. Gathers are issue-bound (by
//    elimination they are ~55-60 us each of the 183.8).
//  - Capacity: bucket edges ~1279+-36, pad adds <=384 -> max ~1664 << 2048.
// Structure otherwise identical to R21: memset(gcnt) + k_scatter
// (fixed-capacity regions + block-level atomic reservations) + k_p2f +
// k_mm + gather_mm(fused mm2) + gather_head(fused head). t' pre-scaled:
//   agg[d] = relu(b + dinv[d] * (sum_e t'[src_e] + t'[d]))
// ---------------------------------------------------------------------------

#define TPB    256
#define TPB1   1024         // scatter block size
#define EBLKS  256          // scatter grid
#define BSH    7            // 128 nodes per bucket
#define BNODES (1 << BSH)
#define CAPSH  11           // 2048 slots per bucket region
#define CAP    (1 << CAPSH)

// k_scatter: per block: LDS hist of its edge chunk -> global reservation
// (one atomic-return per non-empty bucket) -> LDS cursors -> scatter.
__global__ __launch_bounds__(TPB1)
void k_scatter(const int* __restrict__ src, const int* __restrict__ dst,
               int* __restrict__ gcnt, int* __restrict__ ebuf,
               int E, int CH, int NBC) {
    __shared__ int h[1024];     // hist, then absolute cursors
    int tid = threadIdx.x, b = blockIdx.x;
    h[tid] = 0;
    __syncthreads();
    int beg = b * CH, end = min(E, beg + CH);
    if (beg < end) {
        int nfull = (end - beg) & ~3;
        for (int i = beg + tid * 4; i < beg + nfull; i += TPB1 * 4) {
            int4 d = *(const int4*)&dst[i];
            atomicAdd(&h[d.x >> BSH], 1);
            atomicAdd(&h[d.y >> BSH], 1);
            atomicAdd(&h[d.z >> BSH], 1);
            atomicAdd(&h[d.w >> BSH], 1);
        }
        if (tid < (end - beg) - nfull)
            atomicAdd(&h[dst[beg + nfull + tid] >> BSH], 1);
    }
    __syncthreads();
    // reserve: h[c] <- absolute ebuf cursor for this block's share of bucket c
    for (int c = tid; c < NBC; c += TPB1) {
        int n = h[c];
        int base = (n > 0) ? atomicAdd(&gcnt[c], n) : 0;
        h[c] = (c << CAPSH) + base;
    }
    __syncthreads();
    if (beg >= end) return;
    int nfull = (end - beg) & ~3;
    for (int i = beg + tid * 4; i < beg + nfull; i += TPB1 * 4) {
        int4 s4 = *(const int4*)&src[i];
        int4 d4 = *(const int4*)&dst[i];
        int p0 = atomicAdd(&h[d4.x >> BSH], 1);
        int p1 = atomicAdd(&h[d4.y >> BSH], 1);
        int p2 = atomicAdd(&h[d4.z >> BSH], 1);
        int p3 = atomicAdd(&h[d4.w >> BSH], 1);
        ebuf[p0] = (s4.x << BSH) | (d4.x & (BNODES - 1));
        ebuf[p1] = (s4.y << BSH) | (d4.y & (BNODES - 1));
        ebuf[p2] = (s4.z << BSH) | (d4.z & (BNODES - 1));
        ebuf[p3] = (s4.w << BSH) | (d4.w & (BNODES - 1));
    }
    if (tid < (end - beg) - nfull) {
        int i = beg + nfull + tid;
        int d = dst[i];
        int p = atomicAdd(&h[d >> BSH], 1);
        ebuf[p] = (src[i] << BSH) | (d & (BNODES - 1));
    }
}

// k_p2f: per bucket at fixed base: LDS hist -> PADDED scan (4-aligned
// segments) -> row_ptr/row_end/dinv -> rank pass -> colw -> sentinel pads.
__global__ __launch_bounds__(TPB)
void k_p2f(const int* __restrict__ ebuf, const int* __restrict__ gcnt,
           int* __restrict__ row_ptr, int* __restrict__ row_end,
           float* __restrict__ dinv, int* __restrict__ colw,
           int N, int NBC) {
    __shared__ int cnt[BNODES];
    __shared__ int ofs[BNODES];
    __shared__ int s1[TPB];
    int tid = threadIdx.x, c = blockIdx.x;
    int beg = c << CAPSH;
    int end = beg + gcnt[c];
    if (tid < BNODES) cnt[tid] = 0;
    __syncthreads();
    for (int i = beg + tid; i < end; i += TPB)
        atomicAdd(&cnt[ebuf[i] & (BNODES - 1)], 1);
    __syncthreads();
    int a  = (tid < BNODES) ? cnt[tid] : 0;
    int ap = (a + 3) & ~3;              // padded segment length (4-aligned)
    s1[tid] = ap;
    __syncthreads();
    for (int off = 1; off < TPB; off <<= 1) {
        int x = (tid >= off) ? s1[tid - off] : 0;
        __syncthreads();
        s1[tid] += x;
        __syncthreads();
    }
    int ex = s1[tid] - ap;  // exclusive scan of padded lengths
    if (tid < BNODES) {
        int node = (c << BSH) + tid;
        ofs[tid] = beg + ex;            // 4-aligned (beg 2048-aligned)
        if (node < N) {
            row_ptr[node] = beg + ex;
            row_end[node] = beg + ex + a;
            dinv[node]    = rsqrtf((float)(a + 1));
        }
        cnt[tid] = 0;       // reset for rank pass
    }
    __syncthreads();
    // rank + fill (colw = src only)
    for (int i0 = beg + tid; i0 < end; i0 += TPB * 4) {
        int sv[4], dl[4], pos[4];
        int have = 0;
#pragma unroll
        for (int k = 0; k < 4; ++k) {
            int i = i0 + k * TPB;
            if (i < end) {
                int e = ebuf[i];
                sv[k] = e >> BSH;
                dl[k] = e & (BNODES - 1);
                have = k + 1;
            }
        }
#pragma unroll
        for (int k = 0; k < 4; ++k) {
            if (k < have) {
                int r  = atomicAdd(&cnt[dl[k]], 1);
                pos[k] = ofs[dl[k]] + r;
            }
        }
#pragma unroll
        for (int k = 0; k < 4; ++k)
            if (k < have) colw[pos[k]] = sv[k];
    }
    __syncthreads();        // cnt[l] == degree again
    // sentinel-fill pad slots [a, ap) of each segment (<=3 per node)
    if (tid < BNODES) {
        int aa  = cnt[tid];
        int app = (aa + 3) & ~3;
        int o   = ofs[tid];
        for (int j = aa; j < app; ++j) colw[o + j] = N;
    }
}

// Dense GEMM: [n,64] @ [64,64], fp32 in, out = fp16 t' = dinv[row]*(row@W);
// also writes zero sentinel row n.
__launch_bounds__(256)
__global__ void k_mm(const float* __restrict__ in, const float* __restrict__ W,
                     const float* __restrict__ dinv,
                     __half* __restrict__ out, int n) {
    __shared__ float in_s[64 * 68];
    __shared__ float w_s[64 * 64];

    const int tid  = threadIdx.x;
    const int row0 = blockIdx.x * 64;

    for (int i4 = tid; i4 < (64 * 64) / 4; i4 += 256)
        ((float4*)w_s)[i4] = ((const float4*)W)[i4];

    for (int idx = tid; idx < 64 * 16; idx += 256) {
        int r  = idx >> 4;
        int c4 = idx & 15;
        float4 v;
        if (row0 + r < n)
            v = *(const float4*)(in + (size_t)(row0 + r) * 64 + c4 * 4);
        else
            v = make_float4(0.f, 0.f, 0.f, 0.f);
        *(float4*)&in_s[r * 68 + c4 * 4] = v;
    }
    __syncthreads();

    constexpr int CPT = 4;
    const int tx = tid & 15;
    const int ty = tid >> 4;

    float acc[4][CPT];
#pragma unroll
    for (int r = 0; r < 4; ++r)
#pragma unroll
        for (int c = 0; c < CPT; ++c) acc[r][c] = 0.f;

#pragma unroll 4
    for (int k = 0; k < 64; ++k) {
        float b[CPT];
#pragma unroll
        for (int c = 0; c < CPT; ++c) b[c] = w_s[k * 64 + tx * CPT + c];
#pragma unroll
        for (int r = 0; r < 4; ++r) {
            float a = in_s[(ty * 4 + r) * 68 + k];
#pragma unroll
            for (int c = 0; c < CPT; ++c) acc[r][c] = fmaf(a, b[c], acc[r][c]);
        }
    }

#pragma unroll
    for (int r = 0; r < 4; ++r) {
        int row = row0 + ty * 4 + r;
        if (row >= n) continue;
        float dd = dinv[row];
        __half2 p0 = __floats2half2_rn(acc[r][0] * dd, acc[r][1] * dd);
        __half2 p1 = __floats2half2_rn(acc[r][2] * dd, acc[r][3] * dd);
        uint2 u = make_uint2(*(unsigned*)&p0, *(unsigned*)&p1);
        *(uint2*)(out + (size_t)row * 64 + tx * 4) = u;
    }
    // zero sentinel row n (tail edges + pad slots in gather read it)
    if (blockIdx.x == 0 && tid < 16)
        *(uint2*)(out + (size_t)n * 64 + tid * 4) = make_uint2(0u, 0u);
}

// Gather (layer 1) + fused mm2:
// aggrow = relu(b1 + dinv[d]*(sum t'[src] + t'[d]))  (fp16 in LDS)
// t2'[d] = dinv[d] * (aggrow @ W2)   (fp16 out, + zero sentinel row N)
// Edge loop: aligned int4 colw load, no tail guards (pads = sentinel N).
__global__ __launch_bounds__(256)
void k_gather_mm(const int* __restrict__ row_ptr, const int* __restrict__ row_end,
                 const int* __restrict__ colw,
                 const float* __restrict__ dinv, const float* __restrict__ bias,
                 const __half* __restrict__ t, const float* __restrict__ W2,
                 __half* __restrict__ t2, int N) {
    __shared__ float  w_s[64 * 64];     // 16 KB
    __shared__ __half aggs[32][72];     // 4.5 KB

    int tid = threadIdx.x;
    for (int i4 = tid; i4 < (64 * 64) / 4; i4 += 256)
        ((float4*)w_s)[i4] = ((const float4*)W2)[i4];

    int wv   = tid >> 6;
    int lane = tid & 63;
    int g = lane >> 3;
    int p = lane & 7;
    int slot = tid >> 3;                // node slot within block
    int d = blockIdx.x * 32 + wv * 8 + g;

    int beg = 0, end = 0;
    if (d < N) { beg = row_ptr[d]; end = row_end[d]; }

    float acc[8];
#pragma unroll
    for (int k = 0; k < 8; ++k) acc[k] = 0.f;

    for (int e = beg; e < end; e += 4) {
        int4 v = *(const int4*)&colw[e];     // 16B-aligned (4-aligned segs)
        uint4 a0 = *(const uint4*)(t + (size_t)v.x * 64 + p * 8);
        uint4 a1 = *(const uint4*)(t + (size_t)v.y * 64 + p * 8);
        uint4 a2 = *(const uint4*)(t + (size_t)v.z * 64 + p * 8);
        uint4 a3 = *(const uint4*)(t + (size_t)v.w * 64 + p * 8);
        float2 f;
        f = __half22float2(*(__half2*)&a0.x); acc[0] += f.x; acc[1] += f.y;
        f = __half22float2(*(__half2*)&a0.y); acc[2] += f.x; acc[3] += f.y;
        f = __half22float2(*(__half2*)&a0.z); acc[4] += f.x; acc[5] += f.y;
        f = __half22float2(*(__half2*)&a0.w); acc[6] += f.x; acc[7] += f.y;
        f = __half22float2(*(__half2*)&a1.x); acc[0] += f.x; acc[1] += f.y;
        f = __half22float2(*(__half2*)&a1.y); acc[2] += f.x; acc[3] += f.y;
        f = __half22float2(*(__half2*)&a1.z); acc[4] += f.x; acc[5] += f.y;
        f = __half22float2(*(__half2*)&a1.w); acc[6] += f.x; acc[7] += f.y;
        f = __half22float2(*(__half2*)&a2.x); acc[0] += f.x; acc[1] += f.y;
        f = __half22float2(*(__half2*)&a2.y); acc[2] += f.x; acc[3] += f.y;
        f = __half22float2(*(__half2*)&a2.z); acc[4] += f.x; acc[5] += f.y;
        f = __half22float2(*(__half2*)&a2.w); acc[6] += f.x; acc[7] += f.y;
        f = __half22float2(*(__half2*)&a3.x); acc[0] += f.x; acc[1] += f.y;
        f = __half22float2(*(__half2*)&a3.y); acc[2] += f.x; acc[3] += f.y;
        f = __half22float2(*(__half2*)&a3.z); acc[4] += f.x; acc[5] += f.y;
        f = __half22float2(*(__half2*)&a3.w); acc[6] += f.x; acc[7] += f.y;
    }

    if (d < N) {
        float dd = dinv[d];
        uint4 a = *(const uint4*)(t + (size_t)d * 64 + p * 8);
        float4 b0 = *(const float4*)&bias[p * 8];
        float4 b1 = *(const float4*)&bias[p * 8 + 4];
        float2 s0 = __half22float2(*(__half2*)&a.x);
        float2 s1 = __half22float2(*(__half2*)&a.y);
        float2 s2 = __half22float2(*(__half2*)&a.z);
        float2 s3 = __half22float2(*(__half2*)&a.w);
        float o0 = fmaxf(fmaf(dd, acc[0] + s0.x, b0.x), 0.f);
        float o1 = fmaxf(fmaf(dd, acc[1] + s0.y, b0.y), 0.f);
        float o2 = fmaxf(fmaf(dd, acc[2] + s1.x, b0.z), 0.f);
        float o3 = fmaxf(fmaf(dd, acc[3] + s1.y, b0.w), 0.f);
        float o4 = fmaxf(fmaf(dd, acc[4] + s2.x, b1.x), 0.f);
        float o5 = fmaxf(fmaf(dd, acc[5] + s2.y, b1.y), 0.f);
        float o6 = fmaxf(fmaf(dd, acc[6] + s3.x, b1.z), 0.f);
        float o7 = fmaxf(fmaf(dd, acc[7] + s3.y, b1.w), 0.f);
        __half2 h0 = __floats2half2_rn(o0, o1);
        __half2 h1 = __floats2half2_rn(o2, o3);
        __half2 h2 = __floats2half2_rn(o4, o5);
        __half2 h3 = __floats2half2_rn(o6, o7);
        *(uint4*)&aggs[slot][p * 8] = make_uint4(*(unsigned*)&h0, *(unsigned*)&h1,
                                                *(unsigned*)&h2, *(unsigned*)&h3);
    }
    __syncthreads();        // w_s staged + all 8 lanes of each group wrote aggs

    if (d < N) {
        float dd = dinv[d];
        float a0 = 0.f, a1 = 0.f, a2 = 0.f, a3 = 0.f;
        float a4 = 0.f, a5 = 0.f, a6 = 0.f, a7 = 0.f;
#pragma unroll
        for (int k0 = 0; k0 < 64; k0 += 8) {
            uint4 u = *(const uint4*)&aggs[slot][k0];
            float2 f0 = __half22float2(*(__half2*)&u.x);
            float2 f1 = __half22float2(*(__half2*)&u.y);
            float2 f2 = __half22float2(*(__half2*)&u.z);
            float2 f3 = __half22float2(*(__half2*)&u.w);
            float av[8] = {f0.x, f0.y, f1.x, f1.y, f2.x, f2.y, f3.x, f3.y};
#pragma unroll
            for (int j = 0; j < 8; ++j) {
                const float* wr = &w_s[(k0 + j) * 64 + p * 8];   // broadcast/grp
                float4 w0 = *(const float4*)&wr[0];
                float4 w1 = *(const float4*)&wr[4];
                a0 = fmaf(av[j], w0.x, a0);
                a1 = fmaf(av[j], w0.y, a1);
                a2 = fmaf(av[j], w0.z, a2);
                a3 = fmaf(av[j], w0.w, a3);
                a4 = fmaf(av[j], w1.x, a4);
                a5 = fmaf(av[j], w1.y, a5);
                a6 = fmaf(av[j], w1.z, a6);
                a7 = fmaf(av[j], w1.w, a7);
            }
        }
        __half2 q0 = __floats2half2_rn(a0 * dd, a1 * dd);
        __half2 q1 = __floats2half2_rn(a2 * dd, a3 * dd);
        __half2 q2 = __floats2half2_rn(a4 * dd, a5 * dd);
        __half2 q3 = __floats2half2_rn(a6 * dd, a7 * dd);
        uint4 u = make_uint4(*(unsigned*)&q0, *(unsigned*)&q1,
                             *(unsigned*)&q2, *(unsigned*)&q3);
        *(uint4*)(t2 + (size_t)d * 64 + p * 8) = u;
    }
    // zero sentinel row N of t2 (tail/pad edges in gather2 read it)
    if (blockIdx.x == 0 && tid < 16)
        *(uint2*)(t2 + (size_t)N * 64 + tid * 4) = make_uint2(0u, 0u);
}

// Gather (layer 2) + fused classifier head:
// agg_row = relu(b2 + dinv[d]*(sum t'[src] + t'[d]))  (kept in LDS)
// out[d]  = agg_row @ Wl + bl   (each 8-lane group: lane p -> cols 4p..4p+3)
__global__ __launch_bounds__(256)
void k_gather_head(const int* __restrict__ row_ptr, const int* __restrict__ row_end,
                   const int* __restrict__ colw,
                   const float* __restrict__ dinv, const float* __restrict__ bias,
                   const __half* __restrict__ t, const float* __restrict__ Wl,
                   const float* __restrict__ bl, float* __restrict__ out, int N) {
    __shared__ float wl_s[64 * 32];     // 8 KB
    __shared__ float aggs[32][68];      // 8.5 KB, stride 68 (=4 mod 32 banks)

    int tid  = threadIdx.x;
    for (int i4 = tid; i4 < (64 * 32) / 4; i4 += 256)
        ((float4*)wl_s)[i4] = ((const float4*)Wl)[i4];

    int wv   = tid >> 6;
    int lane = tid & 63;
    int g = lane >> 3;
    int p = lane & 7;
    int slot = tid >> 3;                // node slot within block (== wv*8+g)
    int d = blockIdx.x * 32 + wv * 8 + g;

    int beg = 0, end = 0;
    if (d < N) { beg = row_ptr[d]; end = row_end[d]; }

    float acc[8];
#pragma unroll
    for (int k = 0; k < 8; ++k) acc[k] = 0.f;

    for (int e = beg; e < end; e += 4) {
        int4 v = *(const int4*)&colw[e];     // 16B-aligned (4-aligned segs)
        uint4 a0 = *(const uint4*)(t + (size_t)v.x * 64 + p * 8);
        uint4 a1 = *(const uint4*)(t + (size_t)v.y * 64 + p * 8);
        uint4 a2 = *(const uint4*)(t + (size_t)v.z * 64 + p * 8);
        uint4 a3 = *(const uint4*)(t + (size_t)v.w * 64 + p * 8);
        float2 f;
        f = __half22float2(*(__half2*)&a0.x); acc[0] += f.x; acc[1] += f.y;
        f = __half22float2(*(__half2*)&a0.y); acc[2] += f.x; acc[3] += f.y;
        f = __half22float2(*(__half2*)&a0.z); acc[4] += f.x; acc[5] += f.y;
        f = __half22float2(*(__half2*)&a0.w); acc[6] += f.x; acc[7] += f.y;
        f = __half22float2(*(__half2*)&a1.x); acc[0] += f.x; acc[1] += f.y;
        f = __half22float2(*(__half2*)&a1.y); acc[2] += f.x; acc[3] += f.y;
        f = __half22float2(*(__half2*)&a1.z); acc[4] += f.x; acc[5] += f.y;
        f = __half22float2(*(__half2*)&a1.w); acc[6] += f.x; acc[7] += f.y;
        f = __half22float2(*(__half2*)&a2.x); acc[0] += f.x; acc[1] += f.y;
        f = __half22float2(*(__half2*)&a2.y); acc[2] += f.x; acc[3] += f.y;
        f = __half22float2(*(__half2*)&a2.z); acc[4] += f.x; acc[5] += f.y;
        f = __half22float2(*(__half2*)&a2.w); acc[6] += f.x; acc[7] += f.y;
        f = __half22float2(*(__half2*)&a3.x); acc[0] += f.x; acc[1] += f.y;
        f = __half22float2(*(__half2*)&a3.y); acc[2] += f.x; acc[3] += f.y;
        f = __half22float2(*(__half2*)&a3.z); acc[4] += f.x; acc[5] += f.y;
        f = __half22float2(*(__half2*)&a3.w); acc[6] += f.x; acc[7] += f.y;
    }

    if (d < N) {
        float dd = dinv[d];
        uint4 a = *(const uint4*)(t + (size_t)d * 64 + p * 8);
        float4 b0 = *(const float4*)&bias[p * 8];
        float4 b1 = *(const float4*)&bias[p * 8 + 4];
        float2 s0 = __half22float2(*(__half2*)&a.x);
        float2 s1 = __half22float2(*(__half2*)&a.y);
        float2 s2 = __half22float2(*(__half2*)&a.z);
        float2 s3 = __half22float2(*(__half2*)&a.w);
        float o0 = fmaxf(fmaf(dd, acc[0] + s0.x, b0.x), 0.f);
        float o1 = fmaxf(fmaf(dd, acc[1] + s0.y, b0.y), 0.f);
        float o2 = fmaxf(fmaf(dd, acc[2] + s1.x, b0.z), 0.f);
        float o3 = fmaxf(fmaf(dd, acc[3] + s1.y, b0.w), 0.f);
        float o4 = fmaxf(fmaf(dd, acc[4] + s2.x, b1.x), 0.f);
        float o5 = fmaxf(fmaf(dd, acc[5] + s2.y, b1.y), 0.f);
        float o6 = fmaxf(fmaf(dd, acc[6] + s3.x, b1.z), 0.f);
        float o7 = fmaxf(fmaf(dd, acc[7] + s3.y, b1.w), 0.f);
        *(float4*)&aggs[slot][p * 8]     = make_float4(o0, o1, o2, o3);
        *(float4*)&aggs[slot][p * 8 + 4] = make_float4(o4, o5, o6, o7);
    }
    __syncthreads();        // wl_s loaded + all 8 lanes of each group wrote aggs

    if (d < N) {
        float a0 = 0.f, a1 = 0.f, a2 = 0.f, a3 = 0.f;
#pragma unroll 8
        for (int k = 0; k < 64; ++k) {
            float av = aggs[slot][k];                       // broadcast in group
            float4 w = ((const float4*)&wl_s[k * 32])[p];   // conflict-free
            a0 = fmaf(av, w.x, a0);
            a1 = fmaf(av, w.y, a1);
            a2 = fmaf(av, w.z, a2);
            a3 = fmaf(av, w.w, a3);
        }
        float4 bb = *(const float4*)&bl[p * 4];
        *(float4*)&out[(size_t)d * 32 + p * 4] =
            make_float4(a0 + bb.x, a1 + bb.y, a2 + bb.z, a3 + bb.w);
    }
}

extern "C" void kernel_launch(void* const* d_in, const int* in_sizes, int n_in,
                              void* d_out, int out_size, void* d_ws, size_t ws_size,
                              hipStream_t stream) {
    const float* x  = (const float*)d_in[0];
    const int*   ei = (const int*)d_in[1];
    const float* W1 = (const float*)d_in[2];
    const float* b1 = (const float*)d_in[3];
    const float* W2 = (const float*)d_in[4];
    const float* b2 = (const float*)d_in[5];
    const float* Wl = (const float*)d_in[6];
    const float* bl = (const float*)d_in[7];
    float*       out = (float*)d_out;

    const int N = in_sizes[0] / 64;
    const int E = in_sizes[1] / 2;
    const int* srcp = ei;
    const int* dstp = ei + E;

    const int NBC = (N + BNODES - 1) / BNODES;               // buckets (782)
    const int CH  = (((E + EBLKS - 1) / EBLKS) + 3) & ~3;    // chunk, mult of 4

    char*  ws  = (char*)d_ws;
    size_t off = 0;
    auto alloc = [&](size_t bytes) -> void* {
        void* p = (void*)(ws + off);
        off += (bytes + 255) & ~(size_t)255;
        return p;
    };
    int*    gcnt    = (int*)alloc((size_t)NBC * 4);
    int*    ebuf    = (int*)alloc((size_t)NBC * CAP * 4);    // 6.4 MB
    int*    colw    = (int*)alloc((size_t)NBC * CAP * 4);    // 6.4 MB
    int*    row_ptr = (int*)alloc((size_t)N * 4);
    int*    row_end = (int*)alloc((size_t)N * 4);
    float*  dinv    = (float*)alloc((size_t)N * 4);
    __half* t1      = (__half*)alloc((size_t)(N + 1) * 64 * 2);  // +sentinel
    __half* t2      = (__half*)alloc((size_t)(N + 1) * 64 * 2);  // separate:
    // k_gather_mm reads t1 rows (random, cross-block) while writing t2.

    const int nb_mm = (N + 63) / 64;
    const int nb_g  = (N + 31) / 32;

    // --- CSR build: memset + reservation-scatter + per-bucket finish ---
    hipMemsetAsync(gcnt, 0, (size_t)NBC * 4, stream);
    k_scatter<<<EBLKS, TPB1, 0, stream>>>(srcp, dstp, gcnt, ebuf, E, CH, NBC);
    k_p2f    <<<NBC,   TPB,  0, stream>>>(ebuf, gcnt, row_ptr, row_end,
                                          dinv, colw, N, NBC);

    // --- layer 1: t1' = dinv * (x @ W1) ---
    k_mm<<<nb_mm, 256, 0, stream>>>(x, W1, dinv, t1, N);

    // --- gather1 + fused mm2: t2' = dinv * (relu-agg1 @ W2) ---
    k_gather_mm<<<nb_g, 256, 0, stream>>>(row_ptr, row_end, colw, dinv, b1,
                                          t1, W2, t2, N);

    // --- layer 2 gather + fused head: out = relu-agg2 @ Wl + bl ---
    k_gather_head<<<nb_g, 256, 0, stream>>>(row_ptr, row_end, colw, dinv, b2,
                                            t2, Wl, bl, out, N);
}

// Round 11
// 183.045 us; speedup vs baseline: 1.0170x; 1.0073x over previous
//
#include <hip/hip_runtime.h>
#include <hip/hip_fp16.h>
#include <math.h>

// ---------------------------------------------------------------------------
// GCN. R24 = R23 (184.4 ~ R21's 183.8 baseline; int4+sentinel-pad colw kept)
// with the gather latency chain HALVED:
//  - 16 lanes/node (was 8): lane = {p = dim octet} x {h = edge half}.
//    Half h walks int4 chunks e = beg+4h step 8; partials combined by ONE
//    __shfl_xor(acc, 8). Serial dependent iterations drop ~3.9 -> ~1.9
//    per wave (R23 evidence: loop is latency-chain-bound, not issue-bound).
//  - Fused epilogues also use 16 lanes/node (mm2: 4 cols/lane, head: 2),
//    halving their FMA chains. 16 nodes/block, grid 6250.
//  - k_p2f scan: wave __shfl_up prefix + 1 cross-wave combine (2 barriers,
//    was 16).
// Structure otherwise R21/R23: memset(gcnt) + k_scatter (fixed-cap regions
// + block-level atomic reservations) + k_p2f (4-aligned sentinel-padded
// colw) + k_mm + gather_mm(fused mm2) + gather_head(fused head).
// t' pre-scaled: agg[d] = relu(b + dinv[d] * (sum_e t'[src_e] + t'[d]))
// ---------------------------------------------------------------------------

#define TPB    256
#define TPB1   1024         // scatter block size
#define EBLKS  256          // scatter grid
#define BSH    7            // 128 nodes per bucket
#define BNODES (1 << BSH)
#define CAPSH  11           // 2048 slots per bucket region
#define CAP    (1 << CAPSH)

// k_scatter: per block: LDS hist of its edge chunk -> global reservation
// (one atomic-return per non-empty bucket) -> LDS cursors -> scatter.
__global__ __launch_bounds__(TPB1)
void k_scatter(const int* __restrict__ src, const int* __restrict__ dst,
               int* __restrict__ gcnt, int* __restrict__ ebuf,
               int E, int CH, int NBC) {
    __shared__ int h[1024];     // hist, then absolute cursors
    int tid = threadIdx.x, b = blockIdx.x;
    h[tid] = 0;
    __syncthreads();
    int beg = b * CH, end = min(E, beg + CH);
    if (beg < end) {
        int nfull = (end - beg) & ~3;
        for (int i = beg + tid * 4; i < beg + nfull; i += TPB1 * 4) {
            int4 d = *(const int4*)&dst[i];
            atomicAdd(&h[d.x >> BSH], 1);
            atomicAdd(&h[d.y >> BSH], 1);
            atomicAdd(&h[d.z >> BSH], 1);
            atomicAdd(&h[d.w >> BSH], 1);
        }
        if (tid < (end - beg) - nfull)
            atomicAdd(&h[dst[beg + nfull + tid] >> BSH], 1);
    }
    __syncthreads();
    // reserve: h[c] <- absolute ebuf cursor for this block's share of bucket c
    for (int c = tid; c < NBC; c += TPB1) {
        int n = h[c];
        int base = (n > 0) ? atomicAdd(&gcnt[c], n) : 0;
        h[c] = (c << CAPSH) + base;
    }
    __syncthreads();
    if (beg >= end) return;
    int nfull = (end - beg) & ~3;
    for (int i = beg + tid * 4; i < beg + nfull; i += TPB1 * 4) {
        int4 s4 = *(const int4*)&src[i];
        int4 d4 = *(const int4*)&dst[i];
        int p0 = atomicAdd(&h[d4.x >> BSH], 1);
        int p1 = atomicAdd(&h[d4.y >> BSH], 1);
        int p2 = atomicAdd(&h[d4.z >> BSH], 1);
        int p3 = atomicAdd(&h[d4.w >> BSH], 1);
        ebuf[p0] = (s4.x << BSH) | (d4.x & (BNODES - 1));
        ebuf[p1] = (s4.y << BSH) | (d4.y & (BNODES - 1));
        ebuf[p2] = (s4.z << BSH) | (d4.z & (BNODES - 1));
        ebuf[p3] = (s4.w << BSH) | (d4.w & (BNODES - 1));
    }
    if (tid < (end - beg) - nfull) {
        int i = beg + nfull + tid;
        int d = dst[i];
        int p = atomicAdd(&h[d >> BSH], 1);
        ebuf[p] = (src[i] << BSH) | (d & (BNODES - 1));
    }
}

// k_p2f: per bucket at fixed base: LDS hist -> wave-shfl PADDED scan
// (4-aligned segments) -> row_ptr/row_end/dinv -> rank pass -> colw ->
// sentinel pads.
__global__ __launch_bounds__(TPB)
void k_p2f(const int* __restrict__ ebuf, const int* __restrict__ gcnt,
           int* __restrict__ row_ptr, int* __restrict__ row_end,
           float* __restrict__ dinv, int* __restrict__ colw,
           int N, int NBC) {
    __shared__ int cnt[BNODES];
    __shared__ int ofs[BNODES];
    __shared__ int w0sum;
    int tid = threadIdx.x, c = blockIdx.x;
    int beg = c << CAPSH;
    int end = beg + gcnt[c];
    if (tid < BNODES) cnt[tid] = 0;
    __syncthreads();
    for (int i = beg + tid; i < end; i += TPB)
        atomicAdd(&cnt[ebuf[i] & (BNODES - 1)], 1);
    __syncthreads();
    int a  = (tid < BNODES) ? cnt[tid] : 0;
    int ap = (a + 3) & ~3;              // padded segment length (4-aligned)
    // wave-level inclusive scan of ap (lanes 0..63 per wave; tid<128 matter)
    int v = ap;
#pragma unroll
    for (int off = 1; off < 64; off <<= 1) {
        int x = __shfl_up(v, off);
        if ((tid & 63) >= off) v += x;
    }
    if (tid == 63) w0sum = v;           // wave 0 total
    __syncthreads();
    int ex = (v - ap) + ((tid >= 64 && tid < BNODES) ? w0sum : 0);
    if (tid < BNODES) {
        int node = (c << BSH) + tid;
        ofs[tid] = beg + ex;            // 4-aligned (beg 2048-aligned)
        if (node < N) {
            row_ptr[node] = beg + ex;
            row_end[node] = beg + ex + a;
            dinv[node]    = rsqrtf((float)(a + 1));
        }
        cnt[tid] = 0;       // reset for rank pass
    }
    __syncthreads();
    // rank + fill (colw = src only)
    for (int i0 = beg + tid; i0 < end; i0 += TPB * 4) {
        int sv[4], dl[4], pos[4];
        int have = 0;
#pragma unroll
        for (int k = 0; k < 4; ++k) {
            int i = i0 + k * TPB;
            if (i < end) {
                int e = ebuf[i];
                sv[k] = e >> BSH;
                dl[k] = e & (BNODES - 1);
                have = k + 1;
            }
        }
#pragma unroll
        for (int k = 0; k < 4; ++k) {
            if (k < have) {
                int r  = atomicAdd(&cnt[dl[k]], 1);
                pos[k] = ofs[dl[k]] + r;
            }
        }
#pragma unroll
        for (int k = 0; k < 4; ++k)
            if (k < have) colw[pos[k]] = sv[k];
    }
    __syncthreads();        // cnt[l] == degree again
    // sentinel-fill pad slots [a, ap) of each segment (<=3 per node)
    if (tid < BNODES) {
        int aa  = cnt[tid];
        int app = (aa + 3) & ~3;
        int o   = ofs[tid];
        for (int j = aa; j < app; ++j) colw[o + j] = N;
    }
}

// Dense GEMM: [n,64] @ [64,64], fp32 in, out = fp16 t' = dinv[row]*(row@W);
// also writes zero sentinel row n.
__launch_bounds__(256)
__global__ void k_mm(const float* __restrict__ in, const float* __restrict__ W,
                     const float* __restrict__ dinv,
                     __half* __restrict__ out, int n) {
    __shared__ float in_s[64 * 68];
    __shared__ float w_s[64 * 64];

    const int tid  = threadIdx.x;
    const int row0 = blockIdx.x * 64;

    for (int i4 = tid; i4 < (64 * 64) / 4; i4 += 256)
        ((float4*)w_s)[i4] = ((const float4*)W)[i4];

    for (int idx = tid; idx < 64 * 16; idx += 256) {
        int r  = idx >> 4;
        int c4 = idx & 15;
        float4 v;
        if (row0 + r < n)
            v = *(const float4*)(in + (size_t)(row0 + r) * 64 + c4 * 4);
        else
            v = make_float4(0.f, 0.f, 0.f, 0.f);
        *(float4*)&in_s[r * 68 + c4 * 4] = v;
    }
    __syncthreads();

    constexpr int CPT = 4;
    const int tx = tid & 15;
    const int ty = tid >> 4;

    float acc[4][CPT];
#pragma unroll
    for (int r = 0; r < 4; ++r)
#pragma unroll
        for (int c = 0; c < CPT; ++c) acc[r][c] = 0.f;

#pragma unroll 4
    for (int k = 0; k < 64; ++k) {
        float b[CPT];
#pragma unroll
        for (int c = 0; c < CPT; ++c) b[c] = w_s[k * 64 + tx * CPT + c];
#pragma unroll
        for (int r = 0; r < 4; ++r) {
            float a = in_s[(ty * 4 + r) * 68 + k];
#pragma unroll
            for (int c = 0; c < CPT; ++c) acc[r][c] = fmaf(a, b[c], acc[r][c]);
        }
    }

#pragma unroll
    for (int r = 0; r < 4; ++r) {
        int row = row0 + ty * 4 + r;
        if (row >= n) continue;
        float dd = dinv[row];
        __half2 p0 = __floats2half2_rn(acc[r][0] * dd, acc[r][1] * dd);
        __half2 p1 = __floats2half2_rn(acc[r][2] * dd, acc[r][3] * dd);
        uint2 u = make_uint2(*(unsigned*)&p0, *(unsigned*)&p1);
        *(uint2*)(out + (size_t)row * 64 + tx * 4) = u;
    }
    // zero sentinel row n (tail edges + pad slots in gather read it)
    if (blockIdx.x == 0 && tid < 16)
        *(uint2*)(out + (size_t)n * 64 + tid * 4) = make_uint2(0u, 0u);
}

// Gather (layer 1) + fused mm2, 16 lanes/node (p = dim octet, h = edge half):
// aggrow = relu(b1 + dinv[d]*(sum t'[src] + t'[d]))  (fp16 in LDS)
// t2'[d] = dinv[d] * (aggrow @ W2)   (fp16 out, + zero sentinel row N)
__global__ __launch_bounds__(256)
void k_gather_mm(const int* __restrict__ row_ptr, const int* __restrict__ row_end,
                 const int* __restrict__ colw,
                 const float* __restrict__ dinv, const float* __restrict__ bias,
                 const __half* __restrict__ t, const float* __restrict__ W2,
                 __half* __restrict__ t2, int N) {
    __shared__ float  w_s[64 * 64];     // 16 KB
    __shared__ __half aggs[16][72];     // 2.25 KB

    int tid = threadIdx.x;
    for (int i4 = tid; i4 < (64 * 64) / 4; i4 += 256)
        ((float4*)w_s)[i4] = ((const float4*)W2)[i4];

    const int p    = tid & 7;           // dim octet
    const int h    = (tid >> 3) & 1;    // edge half
    const int slot = tid >> 4;          // node slot (0..15)
    const int d    = blockIdx.x * 16 + slot;

    int beg = 0, pe = 0;
    if (d < N) {
        beg = row_ptr[d];
        int end = row_end[d];
        pe  = beg + ((end - beg + 3) & ~3);   // padded end (pads = sentinel N)
    }

    float acc[8];
#pragma unroll
    for (int k = 0; k < 8; ++k) acc[k] = 0.f;

    for (int e = beg + h * 4; e < pe; e += 8) {
        int4 v = *(const int4*)&colw[e];     // 16B-aligned
        uint4 a0 = *(const uint4*)(t + (size_t)v.x * 64 + p * 8);
        uint4 a1 = *(const uint4*)(t + (size_t)v.y * 64 + p * 8);
        uint4 a2 = *(const uint4*)(t + (size_t)v.z * 64 + p * 8);
        uint4 a3 = *(const uint4*)(t + (size_t)v.w * 64 + p * 8);
        float2 f;
        f = __half22float2(*(__half2*)&a0.x); acc[0] += f.x; acc[1] += f.y;
        f = __half22float2(*(__half2*)&a0.y); acc[2] += f.x; acc[3] += f.y;
        f = __half22float2(*(__half2*)&a0.z); acc[4] += f.x; acc[5] += f.y;
        f = __half22float2(*(__half2*)&a0.w); acc[6] += f.x; acc[7] += f.y;
        f = __half22float2(*(__half2*)&a1.x); acc[0] += f.x; acc[1] += f.y;
        f = __half22float2(*(__half2*)&a1.y); acc[2] += f.x; acc[3] += f.y;
        f = __half22float2(*(__half2*)&a1.z); acc[4] += f.x; acc[5] += f.y;
        f = __half22float2(*(__half2*)&a1.w); acc[6] += f.x; acc[7] += f.y;
        f = __half22float2(*(__half2*)&a2.x); acc[0] += f.x; acc[1] += f.y;
        f = __half22float2(*(__half2*)&a2.y); acc[2] += f.x; acc[3] += f.y;
        f = __half22float2(*(__half2*)&a2.z); acc[4] += f.x; acc[5] += f.y;
        f = __half22float2(*(__half2*)&a2.w); acc[6] += f.x; acc[7] += f.y;
        f = __half22float2(*(__half2*)&a3.x); acc[0] += f.x; acc[1] += f.y;
        f = __half22float2(*(__half2*)&a3.y); acc[2] += f.x; acc[3] += f.y;
        f = __half22float2(*(__half2*)&a3.z); acc[4] += f.x; acc[5] += f.y;
        f = __half22float2(*(__half2*)&a3.w); acc[6] += f.x; acc[7] += f.y;
    }
    // combine the two edge halves (lane ^ 8 = same p, other h)
#pragma unroll
    for (int k = 0; k < 8; ++k) acc[k] += __shfl_xor(acc[k], 8);

    if (d < N && h == 0) {
        float dd = dinv[d];
        uint4 a = *(const uint4*)(t + (size_t)d * 64 + p * 8);
        float4 b0 = *(const float4*)&bias[p * 8];
        float4 b1 = *(const float4*)&bias[p * 8 + 4];
        float2 s0 = __half22float2(*(__half2*)&a.x);
        float2 s1 = __half22float2(*(__half2*)&a.y);
        float2 s2 = __half22float2(*(__half2*)&a.z);
        float2 s3 = __half22float2(*(__half2*)&a.w);
        float o0 = fmaxf(fmaf(dd, acc[0] + s0.x, b0.x), 0.f);
        float o1 = fmaxf(fmaf(dd, acc[1] + s0.y, b0.y), 0.f);
        float o2 = fmaxf(fmaf(dd, acc[2] + s1.x, b0.z), 0.f);
        float o3 = fmaxf(fmaf(dd, acc[3] + s1.y, b0.w), 0.f);
        float o4 = fmaxf(fmaf(dd, acc[4] + s2.x, b1.x), 0.f);
        float o5 = fmaxf(fmaf(dd, acc[5] + s2.y, b1.y), 0.f);
        float o6 = fmaxf(fmaf(dd, acc[6] + s3.x, b1.z), 0.f);
        float o7 = fmaxf(fmaf(dd, acc[7] + s3.y, b1.w), 0.f);
        __half2 h0 = __floats2half2_rn(o0, o1);
        __half2 h1 = __floats2half2_rn(o2, o3);
        __half2 h2 = __floats2half2_rn(o4, o5);
        __half2 h3 = __floats2half2_rn(o6, o7);
        *(uint4*)&aggs[slot][p * 8] = make_uint4(*(unsigned*)&h0, *(unsigned*)&h1,
                                                *(unsigned*)&h2, *(unsigned*)&h3);
    }
    __syncthreads();        // w_s staged + aggs written

    if (d < N) {
        float dd = dinv[d];
        const int q = tid & 15;         // col group: cols q*4 .. q*4+3
        float a0 = 0.f, a1 = 0.f, a2 = 0.f, a3 = 0.f;
#pragma unroll
        for (int k0 = 0; k0 < 64; k0 += 8) {
            uint4 u = *(const uint4*)&aggs[slot][k0];
            float2 f0 = __half22float2(*(__half2*)&u.x);
            float2 f1 = __half22float2(*(__half2*)&u.y);
            float2 f2 = __half22float2(*(__half2*)&u.z);
            float2 f3 = __half22float2(*(__half2*)&u.w);
            float av[8] = {f0.x, f0.y, f1.x, f1.y, f2.x, f2.y, f3.x, f3.y};
#pragma unroll
            for (int j = 0; j < 8; ++j) {
                float4 w = *(const float4*)&w_s[(k0 + j) * 64 + q * 4];
                a0 = fmaf(av[j], w.x, a0);
                a1 = fmaf(av[j], w.y, a1);
                a2 = fmaf(av[j], w.z, a2);
                a3 = fmaf(av[j], w.w, a3);
            }
        }
        __half2 q0 = __floats2half2_rn(a0 * dd, a1 * dd);
        __half2 q1 = __floats2half2_rn(a2 * dd, a3 * dd);
        uint2 u = make_uint2(*(unsigned*)&q0, *(unsigned*)&q1);
        *(uint2*)(t2 + (size_t)d * 64 + q * 4) = u;
    }
    // zero sentinel row N of t2 (tail/pad edges in gather2 read it)
    if (blockIdx.x == 0 && tid < 16)
        *(uint2*)(t2 + (size_t)N * 64 + tid * 4) = make_uint2(0u, 0u);
}

// Gather (layer 2) + fused classifier head, 16 lanes/node:
// agg_row = relu(b2 + dinv[d]*(sum t'[src] + t'[d]))  (kept in LDS)
// out[d]  = agg_row @ Wl + bl   (lane q -> cols 2q..2q+1)
__global__ __launch_bounds__(256)
void k_gather_head(const int* __restrict__ row_ptr, const int* __restrict__ row_end,
                   const int* __restrict__ colw,
                   const float* __restrict__ dinv, const float* __restrict__ bias,
                   const __half* __restrict__ t, const float* __restrict__ Wl,
                   const float* __restrict__ bl, float* __restrict__ out, int N) {
    __shared__ float wl_s[64 * 32];     // 8 KB
    __shared__ float aggs[16][68];      // 4.25 KB, stride 68

    int tid  = threadIdx.x;
    for (int i4 = tid; i4 < (64 * 32) / 4; i4 += 256)
        ((float4*)wl_s)[i4] = ((const float4*)Wl)[i4];

    const int p    = tid & 7;
    const int h    = (tid >> 3) & 1;
    const int slot = tid >> 4;
    const int d    = blockIdx.x * 16 + slot;

    int beg = 0, pe = 0;
    if (d < N) {
        beg = row_ptr[d];
        int end = row_end[d];
        pe  = beg + ((end - beg + 3) & ~3);
    }

    float acc[8];
#pragma unroll
    for (int k = 0; k < 8; ++k) acc[k] = 0.f;

    for (int e = beg + h * 4; e < pe; e += 8) {
        int4 v = *(const int4*)&colw[e];
        uint4 a0 = *(const uint4*)(t + (size_t)v.x * 64 + p * 8);
        uint4 a1 = *(const uint4*)(t + (size_t)v.y * 64 + p * 8);
        uint4 a2 = *(const uint4*)(t + (size_t)v.z * 64 + p * 8);
        uint4 a3 = *(const uint4*)(t + (size_t)v.w * 64 + p * 8);
        float2 f;
        f = __half22float2(*(__half2*)&a0.x); acc[0] += f.x; acc[1] += f.y;
        f = __half22float2(*(__half2*)&a0.y); acc[2] += f.x; acc[3] += f.y;
        f = __half22float2(*(__half2*)&a0.z); acc[4] += f.x; acc[5] += f.y;
        f = __half22float2(*(__half2*)&a0.w); acc[6] += f.x; acc[7] += f.y;
        f = __half22float2(*(__half2*)&a1.x); acc[0] += f.x; acc[1] += f.y;
        f = __half22float2(*(__half2*)&a1.y); acc[2] += f.x; acc[3] += f.y;
        f = __half22float2(*(__half2*)&a1.z); acc[4] += f.x; acc[5] += f.y;
        f = __half22float2(*(__half2*)&a1.w); acc[6] += f.x; acc[7] += f.y;
        f = __half22float2(*(__half2*)&a2.x); acc[0] += f.x; acc[1] += f.y;
        f = __half22float2(*(__half2*)&a2.y); acc[2] += f.x; acc[3] += f.y;
        f = __half22float2(*(__half2*)&a2.z); acc[4] += f.x; acc[5] += f.y;
        f = __half22float2(*(__half2*)&a2.w); acc[6] += f.x; acc[7] += f.y;
        f = __half22float2(*(__half2*)&a3.x); acc[0] += f.x; acc[1] += f.y;
        f = __half22float2(*(__half2*)&a3.y); acc[2] += f.x; acc[3] += f.y;
        f = __half22float2(*(__half2*)&a3.z); acc[4] += f.x; acc[5] += f.y;
        f = __half22float2(*(__half2*)&a3.w); acc[6] += f.x; acc[7] += f.y;
    }
#pragma unroll
    for (int k = 0; k < 8; ++k) acc[k] += __shfl_xor(acc[k], 8);

    if (d < N && h == 0) {
        float dd = dinv[d];
        uint4 a = *(const uint4*)(t + (size_t)d * 64 + p * 8);
        float4 b0 = *(const float4*)&bias[p * 8];
        float4 b1 = *(const float4*)&bias[p * 8 + 4];
        float2 s0 = __half22float2(*(__half2*)&a.x);
        float2 s1 = __half22float2(*(__half2*)&a.y);
        float2 s2 = __half22float2(*(__half2*)&a.z);
        float2 s3 = __half22float2(*(__half2*)&a.w);
        float o0 = fmaxf(fmaf(dd, acc[0] + s0.x, b0.x), 0.f);
        float o1 = fmaxf(fmaf(dd, acc[1] + s0.y, b0.y), 0.f);
        float o2 = fmaxf(fmaf(dd, acc[2] + s1.x, b0.z), 0.f);
        float o3 = fmaxf(fmaf(dd, acc[3] + s1.y, b0.w), 0.f);
        float o4 = fmaxf(fmaf(dd, acc[4] + s2.x, b1.x), 0.f);
        float o5 = fmaxf(fmaf(dd, acc[5] + s2.y, b1.y), 0.f);
        float o6 = fmaxf(fmaf(dd, acc[6] + s3.x, b1.z), 0.f);
        float o7 = fmaxf(fmaf(dd, acc[7] + s3.y, b1.w), 0.f);
        *(float4*)&aggs[slot][p * 8]     = make_float4(o0, o1, o2, o3);
        *(float4*)&aggs[slot][p * 8 + 4] = make_float4(o4, o5, o6, o7);
    }
    __syncthreads();        // wl_s loaded + aggs written

    if (d < N) {
        const int q = tid & 15;         // col pair: cols 2q, 2q+1
        float a0 = 0.f, a1 = 0.f;
#pragma unroll 8
        for (int k = 0; k < 64; ++k) {
            float av = aggs[slot][k];                       // broadcast in group
            float2 w = *(const float2*)&wl_s[k * 32 + q * 2];
            a0 = fmaf(av, w.x, a0);
            a1 = fmaf(av, w.y, a1);
        }
        float2 bb = *(const float2*)&bl[q * 2];
        *(float2*)&out[(size_t)d * 32 + q * 2] = make_float2(a0 + bb.x, a1 + bb.y);
    }
}

extern "C" void kernel_launch(void* const* d_in, const int* in_sizes, int n_in,
                              void* d_out, int out_size, void* d_ws, size_t ws_size,
                              hipStream_t stream) {
    const float* x  = (const float*)d_in[0];
    const int*   ei = (const int*)d_in[1];
    const float* W1 = (const float*)d_in[2];
    const float* b1 = (const float*)d_in[3];
    const float* W2 = (const float*)d_in[4];
    const float* b2 = (const float*)d_in[5];
    const float* Wl = (const float*)d_in[6];
    const float* bl = (const float*)d_in[7];
    float*       out = (float*)d_out;

    const int N = in_sizes[0] / 64;
    const int E = in_sizes[1] / 2;
    const int* srcp = ei;
    const int* dstp = ei + E;

    const int NBC = (N + BNODES - 1) / BNODES;               // buckets (782)
    const int CH  = (((E + EBLKS - 1) / EBLKS) + 3) & ~3;    // chunk, mult of 4

    char*  ws  = (char*)d_ws;
    size_t off = 0;
    auto alloc = [&](size_t bytes) -> void* {
        void* p = (void*)(ws + off);
        off += (bytes + 255) & ~(size_t)255;
        return p;
    };
    int*    gcnt    = (int*)alloc((size_t)NBC * 4);
    int*    ebuf    = (int*)alloc((size_t)NBC * CAP * 4);    // 6.4 MB
    int*    colw    = (int*)alloc((size_t)NBC * CAP * 4);    // 6.4 MB
    int*    row_ptr = (int*)alloc((size_t)N * 4);
    int*    row_end = (int*)alloc((size_t)N * 4);
    float*  dinv    = (float*)alloc((size_t)N * 4);
    __half* t1      = (__half*)alloc((size_t)(N + 1) * 64 * 2);  // +sentinel
    __half* t2      = (__half*)alloc((size_t)(N + 1) * 64 * 2);  // separate:
    // k_gather_mm reads t1 rows (random, cross-block) while writing t2.

    const int nb_mm = (N + 63) / 64;
    const int nb_g  = (N + 15) / 16;    // 16 nodes per gather block

    // --- CSR build: memset + reservation-scatter + per-bucket finish ---
    hipMemsetAsync(gcnt, 0, (size_t)NBC * 4, stream);
    k_scatter<<<EBLKS, TPB1, 0, stream>>>(srcp, dstp, gcnt, ebuf, E, CH, NBC);
    k_p2f    <<<NBC,   TPB,  0, stream>>>(ebuf, gcnt, row_ptr, row_end,
                                          dinv, colw, N, NBC);

    // --- layer 1: t1' = dinv * (x @ W1) ---
    k_mm<<<nb_mm, 256, 0, stream>>>(x, W1, dinv, t1, N);

    // --- gather1 + fused mm2: t2' = dinv * (relu-agg1 @ W2) ---
    k_gather_mm<<<nb_g, 256, 0, stream>>>(row_ptr, row_end, colw, dinv, b1,
                                          t1, W2, t2, N);

    // --- layer 2 gather + fused head: out = relu-agg2 @ Wl + bl ---
    k_gather_head<<<nb_g, 256, 0, stream>>>(row_ptr, row_end, colw, dinv, b2,
                                            t2, Wl, bl, out, N);
}